// Round 11
// baseline (42.725 us; speedup 1.0000x reference)
//
#include <hip/hip_runtime.h>

// BootstrapLoss: mean of the top-20% per-pixel (channel-mean) squared errors.
// input/target: [64, 3, 256, 256] fp32. N_pix = 4194304; k = 838861 largest.
//
// Single-pass histogram selection on the float bit pattern (non-negative
// floats order like their uint32 bit patterns). 4096 bins = sign+exp+4
// mantissa bits (bits>>19). LDS: per-bin (count,sum) packed in ONE u64
// ([63:48] count | [47:0] sum, 1/1024 fixed point), 2 copies split by wave
// parity. GLOBAL: u64 per bin ([63:40] cnt | [39:0] sum in units of 1.0),
// 8 slices selected by blockIdx&7 -> per-address atomic chain 512 -> 64,
// plus per-block rotated flush order to break the end-of-kernel convoy.
// k_final sums the 8 slices (L2-resident, ~1us).
//
// History: R4/R5 NO per-block __threadfence finalize (L2 writeback storms).
// R8 packed LDS atomic +2.5us; R9 parity split +1.1us; R10 flush-chain
// halving + packed global +5.6us -> atomic tails, not the read fabric, have
// been the live bottleneck. Read config (512x512, VITER4, 16 waves/CU) is
// occupancy/ILP-insensitive: don't touch.

#define NPIX   (64 * 256 * 256)   // 4194304
#define NV4    (NPIX / 4)         // 1048576
#define HW     65536
#define CHW    196608
#define KTAIL  838861             // 4194304 - int(0.8 * 4194304)
#define NBIN   4096
#define NBLK   512
#define NTHR   512
#define VITER  4                  // NBLK * NTHR * VITER == NV4
#define NSLICE 8

#define FIXSHIFT 10               // LDS sum fixed point = value * 1024
#define CNTSHIFT 48               // LDS pack
#define SUMMASK  ((1ull << CNTSHIFT) - 1ull)
#define GCNTSHIFT 40              // global pack: [63:40] cnt | [39:0] sum (1.0)
#define GSUMMASK  ((1ull << GCNTSHIFT) - 1ull)

__device__ inline float sqf(float x) { return x * x; }

__global__ __launch_bounds__(NTHR)
void k_main(const float4* __restrict__ in, const float4* __restrict__ tg,
            unsigned long long* __restrict__ gpack, int slice_mask) {
  __shared__ unsigned long long h[2][NBIN];   // 64 KB, wave-parity split
  for (int j = threadIdx.x; j < NBIN; j += NTHR) { h[0][j] = 0ull; h[1][j] = 0ull; }
  __syncthreads();

  const int par = (threadIdx.x >> 6) & 1;     // wave parity
  const float S = 65025.0f / 3.0f;            // (255^2)/3
#pragma unroll
  for (int u = 0; u < VITER; ++u) {
    const int i  = (blockIdx.x * VITER + u) * NTHR + threadIdx.x;  // vec4 idx
    const int p  = i << 2;
    const int bb = p >> 16;           // batch (p / HW)
    const int hw = p & (HW - 1);
    const int base4 = (bb * CHW + hw) >> 2;
    float4 a0 = in[base4];
    float4 a1 = in[base4 + HW / 4];
    float4 a2 = in[base4 + HW / 2];
    float4 t0 = tg[base4];
    float4 t1 = tg[base4 + HW / 4];
    float4 t2 = tg[base4 + HW / 2];
    float vv[4];
    vv[0] = (sqf(a0.x - t0.x) + sqf(a1.x - t1.x) + sqf(a2.x - t2.x)) * S;
    vv[1] = (sqf(a0.y - t0.y) + sqf(a1.y - t1.y) + sqf(a2.y - t2.y)) * S;
    vv[2] = (sqf(a0.z - t0.z) + sqf(a1.z - t1.z) + sqf(a2.z - t2.z)) * S;
    vv[3] = (sqf(a0.w - t0.w) + sqf(a1.w - t1.w) + sqf(a2.w - t2.w)) * S;
#pragma unroll
    for (int c = 0; c < 4; ++c) {
      unsigned bin = __float_as_uint(vv[c]) >> 19;
      unsigned long long q =
          (unsigned long long)(vv[c] * (float)(1 << FIXSHIFT) + 0.5f);
      atomicAdd(&h[par][bin], (1ull << CNTSHIFT) | q);
    }
  }
  __syncthreads();

  // flush: merge parity copies (no carry), repack, ONE u64 atomic per
  // nonzero bin into this block's slice, in per-block-rotated order.
  unsigned long long* gp = gpack + (blockIdx.x & slice_mask) * NBIN;
  const int rot = (int)(blockIdx.x * 2897u) & (NBIN - 1);
  for (int jj = threadIdx.x; jj < NBIN; jj += NTHR) {
    int j = (jj + rot) & (NBIN - 1);
    unsigned long long v = h[0][j] + h[1][j];
    if (v) {
      unsigned long long c = v >> CNTSHIFT;
      unsigned long long s =
          ((v & SUMMASK) + (1ull << (FIXSHIFT - 1))) >> FIXSHIFT;
      atomicAdd(&gp[j], (c << GCNTSHIFT) | s);
    }
  }
}

// 256 threads; t owns bins [16t, 16t+16) summed across slices. Hillis-Steele
// suffix scan over 256 chunk totals, then the unique chunk containing the
// k-th largest resolves its 16 bins from registers (static-index unrolled).
__global__ __launch_bounds__(256)
void k_final(const unsigned long long* __restrict__ gpack, int nsl,
             float* __restrict__ out) {
  __shared__ unsigned cumC[256];
  __shared__ double   cumS[256];
  const int t = threadIdx.x;

  unsigned cnt[16];
  double   sm[16];
#pragma unroll
  for (int j = 0; j < 16; ++j) { cnt[j] = 0u; sm[j] = 0.0; }
  for (int s = 0; s < nsl; ++s) {
#pragma unroll
    for (int j = 0; j < 16; ++j) {
      unsigned long long v = gpack[s * NBIN + t * 16 + j];
      cnt[j] += (unsigned)(v >> GCNTSHIFT);
      sm[j]  += (double)(v & GSUMMASK);
    }
  }
  unsigned lc = 0u;
  double   ls = 0.0;
#pragma unroll
  for (int j = 0; j < 16; ++j) { lc += cnt[j]; ls += sm[j]; }
  cumC[t] = lc;
  cumS[t] = ls;
  __syncthreads();

  // inclusive suffix scan: cumC[t] = sum_{t' >= t} chunk_count(t')
#pragma unroll
  for (int off = 1; off < 256; off <<= 1) {
    unsigned c = (t + off < 256) ? cumC[t + off] : 0u;
    double   s = (t + off < 256) ? cumS[t + off] : 0.0;
    __syncthreads();
    cumC[t] += c;
    cumS[t] += s;
    __syncthreads();
  }

  const unsigned above = cumC[t] - lc;   // count in chunks strictly above t
  if (above < (unsigned)KTAIL && cumC[t] >= (unsigned)KTAIL) {
    long   cum = (long)above;
    double ab  = cumS[t] - ls;
    int bsel = -1;
#pragma unroll
    for (int j = 15; j >= 0; --j) {
      if (bsel < 0) {
        if (cum + (long)cnt[j] >= (long)KTAIL || j == 0) {
          bsel = j;
        } else {
          cum += (long)cnt[j];
          ab  += sm[j];
        }
      }
    }
    long r = (long)KTAIL - cum;
    double avg = cnt[bsel] ? sm[bsel] / (double)cnt[bsel] : 0.0;
    out[0] = (float)((ab + (double)r * avg) / (double)KTAIL);
  }
}

extern "C" void kernel_launch(void* const* d_in, const int* in_sizes, int n_in,
                              void* d_out, int out_size, void* d_ws, size_t ws_size,
                              hipStream_t stream) {
  (void)in_sizes; (void)n_in; (void)out_size;
  const float4* in = (const float4*)d_in[0];
  const float4* tg = (const float4*)d_in[1];
  float* out = (float*)d_out;

  // 8 slices if the workspace allows (256 KB), else 1 (proven R10 layout)
  const int nsl = (ws_size >= (size_t)NSLICE * NBIN * 8) ? NSLICE : 1;
  unsigned long long* gpack = (unsigned long long*)d_ws;

  // zero accumulators every call (graph replays reuse ws)
  hipMemsetAsync(gpack, 0, (size_t)nsl * NBIN * 8, stream);

  k_main<<<dim3(NBLK), dim3(NTHR), 0, stream>>>(in, tg, gpack, nsl - 1);
  k_final<<<1, 256, 0, stream>>>(gpack, nsl, out);
}

// Round 12
// 36.325 us; speedup vs baseline: 1.1762x; 1.1762x over previous
//
#include <hip/hip_runtime.h>

// BootstrapLoss: mean of the top-20% per-pixel (channel-mean) squared errors.
// input/target: [64, 3, 256, 256] fp32. N_pix = 4194304; k = 838861 largest.
//
// Single-pass histogram selection on the float bit pattern (non-negative
// floats order like their uint32 bit patterns). 4096 bins = sign+exp+4
// mantissa bits (bits>>19). LDS: per-bin (count,sum) packed in ONE u64
// ([63:48] count | [47:0] sum in 1/1024 fixed point), 2 copies split by
// wave parity (halves hot-bin contention). GLOBAL: one u64 per bin,
// [63:40] count | [39:0] sum in units of 1.0 (count<=4.2M<2^24; tail sum
// ~1.9e10 < 2^40; per-flush rounding <=0.5 -> error <<0.1 on the mean;
// measured absmax 0.0).
//
// FINAL CONFIG (= R10, measured 36.4us). Ladder: 106.5 -> 59.7 (fuse to
// single pass) -> 48.4 (parallel k_final) -> 43.2 (packed LDS atomic)
// -> 42.0 (wave-parity split) -> 36.4 (512 blocks + packed global u64).
// Dead ends, measured: fused __threadfence finalize (5-10x regression,
// L2 writeback storms); occupancy 16->32 waves/CU (null); load-batch ILP
// restructure (null, compiler re-sinks); 8-way sliced global flush +
// rotation (-6.3us: memset/k_final overhead + scattered atomic lines).
// Structural wall: 402 MB mandatory read at ~12 TB/s effective (mixed
// L3/HBM fabric), atomic tails fully amortized.

#define NPIX   (64 * 256 * 256)   // 4194304
#define NV4    (NPIX / 4)         // 1048576
#define HW     65536
#define CHW    196608
#define KTAIL  838861             // 4194304 - int(0.8 * 4194304)
#define NBIN   4096
#define NBLK   512
#define NTHR   512
#define VITER  4                  // NBLK * NTHR * VITER == NV4

#define FIXSHIFT 10               // LDS sum fixed point = value * 1024
#define CNTSHIFT 48               // LDS pack
#define SUMMASK  ((1ull << CNTSHIFT) - 1ull)
#define GCNTSHIFT 40              // global pack: [63:40] cnt | [39:0] sum (1.0)
#define GSUMMASK  ((1ull << GCNTSHIFT) - 1ull)

__device__ inline float sqf(float x) { return x * x; }

__global__ __launch_bounds__(NTHR)
void k_main(const float4* __restrict__ in, const float4* __restrict__ tg,
            unsigned long long* __restrict__ gpack) {
  __shared__ unsigned long long h[2][NBIN];   // 64 KB, wave-parity split
  for (int j = threadIdx.x; j < NBIN; j += NTHR) { h[0][j] = 0ull; h[1][j] = 0ull; }
  __syncthreads();

  const int par = (threadIdx.x >> 6) & 1;     // wave parity
  const float S = 65025.0f / 3.0f;            // (255^2)/3
#pragma unroll
  for (int u = 0; u < VITER; ++u) {
    const int i  = (blockIdx.x * VITER + u) * NTHR + threadIdx.x;  // vec4 idx
    const int p  = i << 2;
    const int bb = p >> 16;           // batch (p / HW)
    const int hw = p & (HW - 1);
    const int base4 = (bb * CHW + hw) >> 2;
    float4 a0 = in[base4];
    float4 a1 = in[base4 + HW / 4];
    float4 a2 = in[base4 + HW / 2];
    float4 t0 = tg[base4];
    float4 t1 = tg[base4 + HW / 4];
    float4 t2 = tg[base4 + HW / 2];
    float vv[4];
    vv[0] = (sqf(a0.x - t0.x) + sqf(a1.x - t1.x) + sqf(a2.x - t2.x)) * S;
    vv[1] = (sqf(a0.y - t0.y) + sqf(a1.y - t1.y) + sqf(a2.y - t2.y)) * S;
    vv[2] = (sqf(a0.z - t0.z) + sqf(a1.z - t1.z) + sqf(a2.z - t2.z)) * S;
    vv[3] = (sqf(a0.w - t0.w) + sqf(a1.w - t1.w) + sqf(a2.w - t2.w)) * S;
#pragma unroll
    for (int c = 0; c < 4; ++c) {
      unsigned bin = __float_as_uint(vv[c]) >> 19;
      unsigned long long q =
          (unsigned long long)(vv[c] * (float)(1 << FIXSHIFT) + 0.5f);
      atomicAdd(&h[par][bin], (1ull << CNTSHIFT) | q);
    }
  }
  __syncthreads();

  // flush: merge parity copies (no carry: cnt<=4096 in 16b, sum<2^48) and
  // repack to global layout with ONE u64 atomic per nonzero bin.
  for (int j = threadIdx.x; j < NBIN; j += NTHR) {
    unsigned long long v = h[0][j] + h[1][j];
    if (v) {
      unsigned long long c = v >> CNTSHIFT;
      // round LDS fixed-point (x1024) to integer units of 1.0
      unsigned long long s =
          ((v & SUMMASK) + (1ull << (FIXSHIFT - 1))) >> FIXSHIFT;
      atomicAdd(&gpack[j], (c << GCNTSHIFT) | s);
    }
  }
}

// 256 threads; t owns bins [16t, 16t+16). Hillis-Steele suffix scan over the
// 256 chunk totals (count + sum), then the unique chunk containing the k-th
// largest resolves its 16 bins from registers (static-index unrolled).
__global__ __launch_bounds__(256)
void k_final(const unsigned long long* __restrict__ gpack,
             float* __restrict__ out) {
  __shared__ unsigned cumC[256];
  __shared__ double   cumS[256];
  const int t = threadIdx.x;

  unsigned cnt[16];
  double   sm[16];
  unsigned lc = 0u;
  double   ls = 0.0;
#pragma unroll
  for (int j = 0; j < 16; ++j) {
    unsigned long long v = gpack[t * 16 + j];
    cnt[j] = (unsigned)(v >> GCNTSHIFT);
    sm[j]  = (double)(v & GSUMMASK);
    lc += cnt[j];
    ls += sm[j];
  }
  cumC[t] = lc;
  cumS[t] = ls;
  __syncthreads();

  // inclusive suffix scan: cumC[t] = sum_{t' >= t} chunk_count(t')
#pragma unroll
  for (int off = 1; off < 256; off <<= 1) {
    unsigned c = (t + off < 256) ? cumC[t + off] : 0u;
    double   s = (t + off < 256) ? cumS[t + off] : 0.0;
    __syncthreads();
    cumC[t] += c;
    cumS[t] += s;
    __syncthreads();
  }

  const unsigned above = cumC[t] - lc;   // count in chunks strictly above t
  if (above < (unsigned)KTAIL && cumC[t] >= (unsigned)KTAIL) {
    long   cum = (long)above;
    double ab  = cumS[t] - ls;
    int bsel = -1;
#pragma unroll
    for (int j = 15; j >= 0; --j) {
      if (bsel < 0) {
        if (cum + (long)cnt[j] >= (long)KTAIL || j == 0) {
          bsel = j;
        } else {
          cum += (long)cnt[j];
          ab  += sm[j];
        }
      }
    }
    long r = (long)KTAIL - cum;
    double avg = cnt[bsel] ? sm[bsel] / (double)cnt[bsel] : 0.0;
    out[0] = (float)((ab + (double)r * avg) / (double)KTAIL);
  }
}

extern "C" void kernel_launch(void* const* d_in, const int* in_sizes, int n_in,
                              void* d_out, int out_size, void* d_ws, size_t ws_size,
                              hipStream_t stream) {
  (void)in_sizes; (void)n_in; (void)out_size; (void)ws_size;
  const float4* in = (const float4*)d_in[0];
  const float4* tg = (const float4*)d_in[1];
  float* out = (float*)d_out;

  unsigned long long* gpack = (unsigned long long*)d_ws;   // 32 KB

  // zero accumulators every call (graph replays reuse ws)
  hipMemsetAsync(gpack, 0, NBIN * 8, stream);

  k_main<<<dim3(NBLK), dim3(NTHR), 0, stream>>>(in, tg, gpack);
  k_final<<<1, 256, 0, stream>>>(gpack, out);
}